// Round 3
// baseline (140.855 us; speedup 1.0000x reference)
//
#include <hip/hip_runtime.h>
#include <hip/hip_bf16.h>

typedef __attribute__((ext_vector_type(8))) short short8;      // 8 bf16 MFMA operand
typedef __attribute__((ext_vector_type(4))) float f32x4;
typedef __attribute__((ext_vector_type(4))) unsigned short u16x4;

// LDS: one 72 KB region. Phase 1-2: X stage [144 rows][512 B] swizzled bf16.
// Phase 3+: partials [8][25][16] f32 (12800 B) + alphas [25][16] f32 (1600 B)
// ALIASED onto the stage region (all stage reads complete before first write,
// enforced by the post-GEMM __syncthreads()).
#define STAGE_BYTES (144 * 512)                    // 73728
#define PART_OFF    0                              // [wave][edge][graph] f32
#define ALPHA_OFF   (8 * 25 * 16 * 4)              // 12800
#define LDS_BYTES   STAGE_BYTES                    // 73728 -> 2 blocks/CU

__device__ __forceinline__ unsigned short f2bf(float f) {
    unsigned int u = __float_as_uint(f);
    unsigned int r = (u + 0x7fffu + ((u >> 16) & 1u)) >> 16;   // RNE
    return (unsigned short)r;
}

// static graph tables (compile-time foldable in unrolled loops)
constexpr int C_SRC[25] = {0,1,0,3,0,5,0,7,1,2,3,4,5,6,7,8, 0,1,2,3,4,5,6,7,8};
constexpr int C_DST[25] = {1,0,3,0,5,0,7,0,2,1,4,3,6,5,8,7, 0,1,2,3,4,5,6,7,8};
constexpr int C_NINC[9]  = {5,3,2,3,2,3,2,3,2};
constexpr int C_IOFF[9]  = {0,5,8,10,13,15,18,20,23};
constexpr int C_INCE[25] = {1,3,5,7,16, 0,9,17, 8,18, 2,11,19, 10,20, 4,13,21, 12,22, 6,15,23, 14,24};
constexpr int C_INCS[25] = {1,3,5,7,0,  0,2,1,  1,2,  0,4,3,  3,4,  0,6,5,  5,6,  0,8,7,  7,8};
// runtime-indexed copies (softmax phase) in global const memory, not scratch
__device__ const int D_NINC[9]  = {5,3,2,3,2,3,2,3,2};
__device__ const int D_IOFF[9]  = {0,5,8,10,13,15,18,20,23};
__device__ const int D_INCE[25] = {1,3,5,7,16, 0,9,17, 8,18, 2,11,19, 10,20, 4,13,21, 12,22, 6,15,23, 14,24};

// WT[n][k] = (n<256 ? W_l[k][n] : W_r[k][n-256]) as bf16 (B-fragments contiguous)
__global__ void convert_w_kernel(const float* __restrict__ Wl,
                                 const float* __restrict__ Wr,
                                 unsigned short* __restrict__ WT) {
    int n = blockIdx.x;      // 0..511
    int k = threadIdx.x;     // 0..255
    float v = (n < 256) ? Wl[k * 256 + n] : Wr[k * 256 + (n - 256)];
    WT[n * 256 + k] = f2bf(v);
}

__global__ __launch_bounds__(512, 2) void gat_fused_kernel(
        const float* __restrict__ x,
        const unsigned short* __restrict__ WT,
        const float* __restrict__ att,
        const float* __restrict__ bias,
        float* __restrict__ out) {
    __shared__ __align__(16) char smem[LDS_BYTES];
    float* partials = (float*)(smem + PART_OFF);   // [wave][edge][graph] (aliases stage)
    float* alphas   = (float*)(smem + ALPHA_OFF);  // [edge][graph]       (aliases stage)

    const int tid  = threadIdx.x;
    const int lane = tid & 63;
    const int w    = tid >> 6;        // 8 waves; wave owns XL cols [32w,32w+32) + XR same
    const int gl   = lane >> 4;       // row group: graphs 4*gl..4*gl+3
    const int li   = lane & 15;       // column-within-tile
    const int blk  = blockIdx.x;

    // per-lane att/bias scalars for this wave's two 16-col tiles
    const int c0 = 32 * w + li, c1 = c0 + 16;
    const float attc0 = att[c0], attc1 = att[c1];
    const float bc0   = bias[c0], bc1 = bias[c1];

    // ---- phase 1: stage x -> LDS bf16, node-major rows (row = node*16 + g), swizzled ----
    const float* xblk = x + (size_t)blk * 36864;
    {
        f32x4 xv[18];
        #pragma unroll
        for (int it = 0; it < 18; ++it)
            xv[it] = *(const f32x4*)(xblk + it * 2048 + tid * 4);
        #pragma unroll
        for (int it = 0; it < 18; ++it) {
            int f    = it * 2048 + tid * 4;
            int gr   = f >> 8;              // g*9 + node
            int c    = f & 255;
            int g    = gr / 9;
            int node = gr - g * 9;
            int srow = node * 16 + g;       // srow & 15 == g
            u16x4 pk = { f2bf(xv[it][0]), f2bf(xv[it][1]), f2bf(xv[it][2]), f2bf(xv[it][3]) };
            *(u16x4*)(smem + srow * 512 + ((2 * c) ^ (g << 4))) = pk;
        }
    }
    __syncthreads();

    // ---- phase 2: GEMM -> registers. aL = x@W_l slice, aR = x@W_r slice ----
    const f32x4 ZERO = {0.f, 0.f, 0.f, 0.f};
    f32x4 aL[9][2], aR[9][2];
    #pragma unroll
    for (int m = 0; m < 9; ++m) {
        aL[m][0] = ZERO; aL[m][1] = ZERO; aR[m][0] = ZERO; aR[m][1] = ZERO;
    }
    const unsigned short* WL0 = WT + (size_t)((32 * w + li) * 256 + gl * 8);
    const unsigned short* WL1 = WL0 + 16 * 256;
    const unsigned short* WR0 = WL0 + 256 * 256;
    const unsigned short* WR1 = WR0 + 16 * 256;

    #pragma unroll
    for (int kc = 0; kc < 8; ++kc) {
        short8 bl0 = *(const short8*)(WL0 + kc * 32);
        short8 bl1 = *(const short8*)(WL1 + kc * 32);
        short8 br0 = *(const short8*)(WR0 + kc * 32);
        short8 br1 = *(const short8*)(WR1 + kc * 32);
        const int inner = ((kc * 64) + (gl * 16)) ^ (li << 4);
        short8 am[9];
        #pragma unroll
        for (int m = 0; m < 9; ++m)
            am[m] = *(const short8*)(smem + (m * 16 + li) * 512 + inner);
        #pragma unroll
        for (int m = 0; m < 9; ++m) {
            aL[m][0] = __builtin_amdgcn_mfma_f32_16x16x32_bf16(am[m], bl0, aL[m][0], 0, 0, 0);
            aL[m][1] = __builtin_amdgcn_mfma_f32_16x16x32_bf16(am[m], bl1, aL[m][1], 0, 0, 0);
            aR[m][0] = __builtin_amdgcn_mfma_f32_16x16x32_bf16(am[m], br0, aR[m][0], 0, 0, 0);
            aR[m][1] = __builtin_amdgcn_mfma_f32_16x16x32_bf16(am[m], br1, aR[m][1], 0, 0, 0);
        }
    }
    // D-frag: col = li (within tile), row = 4*gl + r = graph.
    __syncthreads();   // all stage-region reads done; region becomes partials/alphas

    // ---- phase 3: per-edge scores, fully in registers + 16-lane butterfly ----
    #pragma unroll
    for (int e = 0; e < 25; ++e) {
        const int s = C_SRC[e], d = C_DST[e];
        float p0 = 0.f, p1 = 0.f, p2 = 0.f, p3 = 0.f;
        #pragma unroll
        for (int nt = 0; nt < 2; ++nt) {
            const float ac = nt ? attc1 : attc0;
            #pragma unroll
            for (int r = 0; r < 4; ++r) {
                float v  = aL[s][nt][r] + aR[d][nt][r];
                float lr = fmaxf(v, 0.2f * v);          // LeakyReLU(0.2)
                float t  = ac * lr;
                if (r == 0) p0 += t; else if (r == 1) p1 += t;
                else if (r == 2) p2 += t; else p3 += t;
            }
        }
        #pragma unroll
        for (int m = 1; m < 16; m <<= 1) {              // sum over the 16 cols of this wave
            p0 += __shfl_xor(p0, m);
            p1 += __shfl_xor(p1, m);
            p2 += __shfl_xor(p2, m);
            p3 += __shfl_xor(p3, m);
        }
        if (li == 0) {
            f32x4 pk = {p0, p1, p2, p3};
            *(f32x4*)(partials + (w * 25 + e) * 16 + 4 * gl) = pk;
        }
    }
    __syncthreads();

    // ---- phase 4: segment softmax, one thread per (node, graph) ----
    if (tid < 144) {
        int n = tid >> 4, g = tid & 15;
        int off = D_IOFF[n], cnt = D_NINC[n];
        float mx = -1e30f;
        for (int i = 0; i < cnt; ++i) {
            int e = D_INCE[off + i];
            float s = 0.f;
            #pragma unroll
            for (int ww = 0; ww < 8; ++ww) s += partials[(ww * 25 + e) * 16 + g];
            alphas[e * 16 + g] = s;                     // scratch: raw score
            mx = fmaxf(mx, s);
        }
        float ssum = 0.f;
        for (int i = 0; i < cnt; ++i)
            ssum += __expf(alphas[D_INCE[off + i] * 16 + g] - mx);
        float inv = 1.f / ssum;
        for (int i = 0; i < cnt; ++i) {
            int e = D_INCE[off + i];
            alphas[e * 16 + g] = __expf(alphas[e * 16 + g] - mx) * inv;
        }
    }
    __syncthreads();

    // ---- phase 5: aggregate in registers (alpha is tile-diagonal in node-major order) ----
    #pragma unroll
    for (int n = 0; n < 9; ++n) {
        f32x4 o0 = {bc0, bc0, bc0, bc0};
        f32x4 o1 = {bc1, bc1, bc1, bc1};
        #pragma unroll
        for (int i = 0; i < C_NINC[n]; ++i) {
            const int e  = C_INCE[C_IOFF[n] + i];
            const int sn = C_INCS[C_IOFF[n] + i];
            f32x4 al = *(const f32x4*)(alphas + e * 16 + 4 * gl);   // alpha for graphs 4gl..4gl+3
            #pragma unroll
            for (int r = 0; r < 4; ++r) {
                o0[r] += al[r] * aL[sn][0][r];
                o1[r] += al[r] * aL[sn][1][r];
            }
        }
        #pragma unroll
        for (int r = 0; r < 4; ++r) {
            size_t row = (size_t)(blk * 16 + 4 * gl + r) * 9 + n;
            out[row * 256 + c0] = o0[r];
            out[row * 256 + c1] = o1[r];
        }
    }
}

extern "C" void kernel_launch(void* const* d_in, const int* in_sizes, int n_in,
                              void* d_out, int out_size, void* d_ws, size_t ws_size,
                              hipStream_t stream) {
    const float* x    = (const float*)d_in[0];
    const float* Wl   = (const float*)d_in[1];
    const float* Wr   = (const float*)d_in[2];
    const float* att  = (const float*)d_in[3];
    const float* bias = (const float*)d_in[4];
    float* out = (float*)d_out;
    unsigned short* WT = (unsigned short*)d_ws;      // 512*256 bf16 = 256 KB

    convert_w_kernel<<<512, 256, 0, stream>>>(Wl, Wr, WT);
    gat_fused_kernel<<<1024, 512, 0, stream>>>(x, WT, att, bias, out);
}